// Round 4
// baseline (554.823 us; speedup 1.0000x reference)
//
#include <hip/hip_runtime.h>
#include <hip/hip_bf16.h>

// Problem: out[M,N] = data[M,K] @ (weight*mask)[N,K]^T + bias[N]
// M = 8192, N = 4096, K = 4096, fp32 in/out, bf16 MFMA internally.
//
// R7: R6 pipeline + (a) 32x32x16 MFMA (2382 vs 2075 TF ceiling, half the
// MFMA instruction count, deeper per-MFMA shadow for LDS overlap), and
// (b) race-clean staging: R6's p2/p3 stages could in principle land on rows
// whose p1-issued reads were still in flight (saved only by DMA latency >>
// ds drain). Correct region-freedom: A-region (all 256 rows) fully read by
// all waves after BAR2; B-region after BAR3. So stage A(kt+2) both halves
// at p3, B(kt+2) both halves at p4.
//
// Per tile kt (buffer c = kt&1), quadrant order Q00,Q10,Q11,Q01:
//   p1: read A1c (8 ds)                  | MFMA Q00(aC,b0) | BAR1
//   p2: read B1c (4 ds)                  | MFMA Q10(aN,b0) | BAR2
//   p3: stage A0+A1(kt+2) (4 vm); VM4    | MFMA Q11(aN,b1) | BAR3
//   p4: stage B0+B1(kt+2) (4 vm); SB0;
//       read A0n,B0n (12 ds, buffer c^1) | MFMA Q01(aC,b1) | BAR4
// vmcnt(4) at p3: outstanding = kt+1's 8 (older) + kt+2's 4 A-stages ->
// wait to 4 => kt+1 fully in LDS before p4's cross-tile reads (which come
// after BAR3 = all waves past VM4). Counted vmcnt never 0 in main loop (T4).
// A-slot ping-pong -> main loop unrolled by 2 with static slot names.
// 32x32x16 layouts: A/B row=lane&31, k=(lane>>5)*8+e (family extension of
// the proven 16x16x32 mapping); C/D col=lane&31, row=(reg&3)+8*(reg>>2)+
// 4*(lane>>5) [measured m74/m101]. T2 swizzle on 16B slots kept (row&7 ==
// lane&7 for all LDS rows since row bases are multiples of 32).

#define M_TOT 8192
#define N_TOT 4096
#define K_TOT 4096

#define BM 256
#define BN 256
#define BK 64
#define NT (K_TOT / BK)   // 64 K-tiles

typedef __attribute__((ext_vector_type(8))) short short8;
typedef __attribute__((ext_vector_type(16))) float floatx16;

// ---- fp32 -> bf16 round-to-nearest-even ----
__device__ inline unsigned short f2bf(float f) {
    unsigned int u = __builtin_bit_cast(unsigned int, f);
    u += 0x7fffu + ((u >> 16) & 1u);
    return (unsigned short)(u >> 16);
}

// data[M*K] fp32 -> bf16  (exact grid, one float4 per thread)
__global__ __launch_bounds__(256) void cast_data_kernel(const float4* __restrict__ in,
                                                        ushort4* __restrict__ out) {
    int i = blockIdx.x * 256 + threadIdx.x;
    float4 f = in[i];
    ushort4 o;
    o.x = f2bf(f.x); o.y = f2bf(f.y); o.z = f2bf(f.z); o.w = f2bf(f.w);
    out[i] = o;
}

// (weight * mask)[N*K] fp32 -> bf16
__global__ __launch_bounds__(256) void cast_w_kernel(const float4* __restrict__ w,
                                                     const float4* __restrict__ m,
                                                     ushort4* __restrict__ out) {
    int i = blockIdx.x * 256 + threadIdx.x;
    float4 a = w[i];
    float4 b = m[i];
    ushort4 o;
    o.x = f2bf(a.x * b.x); o.y = f2bf(a.y * b.y);
    o.z = f2bf(a.z * b.z); o.w = f2bf(a.w * b.w);
    out[i] = o;
}

// ---- async global->LDS, 16B per lane (LDS dst linear: base + lane*16) ----
__device__ inline void load_lds16(const unsigned short* g, unsigned short* l) {
    __builtin_amdgcn_global_load_lds(
        (__attribute__((address_space(1))) void*)(const_cast<unsigned short*>(g)),
        (__attribute__((address_space(3))) void*)(l),
        16, 0, 0);
}

#define BAR()   __builtin_amdgcn_s_barrier()
#define SB0()   __builtin_amdgcn_sched_barrier(0)
#define VM8()   asm volatile("s_waitcnt vmcnt(8)" ::: "memory")
#define VM4()   asm volatile("s_waitcnt vmcnt(4)" ::: "memory")
#define VM0()   asm volatile("s_waitcnt vmcnt(0)" ::: "memory")

__global__ __launch_bounds__(512, 2) void gemm_bt_kernel(const unsigned short* __restrict__ A,
                                                         const unsigned short* __restrict__ W,
                                                         const float* __restrict__ bias,
                                                         float* __restrict__ out) {
    // 2 buffers x 256 rows x 64 cols bf16 for A and B: 64 KiB + 64 KiB.
    __shared__ __align__(16) unsigned short As[2 * BM * BK];
    __shared__ __align__(16) unsigned short Bs[2 * BN * BK];

    const int t = threadIdx.x;
    const int m0 = blockIdx.y * BM;
    const int n0 = blockIdx.x * BN;

    const int lane  = t & 63;
    const int wv    = t >> 6;            // wave 0..7
    const int wm    = (wv >> 2) * 128;   // wave m-offset (0/128)
    const int wn    = (wv & 3) * 64;     // wave n-offset (0/64/128/192)
    const int l31   = lane & 31;         // 32x32 row/col within fragment
    const int khalf = lane >> 5;         // k-half of this lane (0/1)
    const int rx    = lane & 7;          // read-side swizzle ( == row&7 )

    // ---- staging geometry (proven R3/R5/R6 pattern) ----
    // half-tile = 128 rows x 8 slots(16B) = 1024 chunks; thread t writes linear
    // LDS chunks t and t+512. Phys slot (t&7) of row (t>>3) holds logical slot
    // (t&7)^(row&7) => pre-swizzle the GLOBAL source. Row+64: same formula.
    const int srow  = t >> 3;                       // 0..63
    const int lslot = (t & 7) ^ (srow & 7);
    const size_t thr_off = (size_t)srow * K_TOT + (size_t)lslot * 8;  // ushorts

    const unsigned short* Ag = A + (size_t)m0 * K_TOT + thr_off;
    const unsigned short* Bg = W + (size_t)n0 * K_TOT + thr_off;

    auto stageA = [&](int ts, int h) {
        const unsigned short* s = Ag + (size_t)(h * 128) * K_TOT + ts * BK;
        unsigned short* d = As + (ts & 1) * (BM * BK) + h * (128 * BK) + t * 8;
        load_lds16(s, d);
        load_lds16(s + (size_t)64 * K_TOT, d + 512 * 8);
    };
    auto stageB = [&](int ts, int h) {
        const unsigned short* s = Bg + (size_t)(h * 128) * K_TOT + ts * BK;
        unsigned short* d = Bs + (ts & 1) * (BN * BK) + h * (128 * BK) + t * 8;
        load_lds16(s, d);
        load_lds16(s + (size_t)64 * K_TOT, d + 512 * 8);
    };

    // ---- fragment register slots (32x32x16: 8 bf16 = 1 short8 per operand) ----
    short8 aX[8], aY[8];   // two A slots (mf*4+ks), ping-pong roles (64 VGPR)
    short8 b0[4], b1[4];   // B halves, [ks], fixed roles           (32 VGPR)

    auto readA = [&](int buf, int mh, short8 (&d)[8]) {
#pragma unroll
        for (int mf = 0; mf < 2; mf++) {
            const unsigned short* base =
                As + buf * (BM * BK) + (wm + mh * 64 + mf * 32 + l31) * BK;
#pragma unroll
            for (int ks = 0; ks < 4; ks++)
                d[mf * 4 + ks] = *(const short8*)(base + (((ks * 2 + khalf) ^ rx) << 3));
        }
    };
    auto readB = [&](int buf, int nh, short8 (&d)[4]) {
        const unsigned short* base =
            Bs + buf * (BN * BK) + (wn + nh * 32 + l31) * BK;
#pragma unroll
        for (int ks = 0; ks < 4; ks++)
            d[ks] = *(const short8*)(base + (((ks * 2 + khalf) ^ rx) << 3));
    };

    floatx16 acc[4][2];
#pragma unroll
    for (int i = 0; i < 4; i++)
#pragma unroll
        for (int j = 0; j < 2; j++) {
            floatx16 z = {0,0,0,0,0,0,0,0,0,0,0,0,0,0,0,0};
            acc[i][j] = z;
        }

    auto mmaQ = [&](short8 (&a)[8], short8 (&b)[4], int mh, int nh) {
        __builtin_amdgcn_s_setprio(1);
#pragma unroll
        for (int mf = 0; mf < 2; mf++)
#pragma unroll
            for (int ks = 0; ks < 4; ks++)
                acc[mh * 2 + mf][nh] = __builtin_amdgcn_mfma_f32_32x32x16_bf16(
                    a[mf * 4 + ks], b[ks], acc[mh * 2 + mf][nh], 0, 0, 0);
        __builtin_amdgcn_s_setprio(0);
    };

    // mode 0: stage kt+2 (A@p3, B@p4), VM4, cross-tile reads
    // mode 1: no staging, VM0 at p3, cross-tile reads (tile NT-2)
    // mode 2: compute only (tile NT-1)
    auto tileT = [&](int kt, short8 (&aC)[8], short8 (&aN)[8], int mode) {
        const int buf = kt & 1;
        // p1: issue A1c reads | MFMA Q00(aC=A0, b0=B0)
        readA(buf, 1, aN);
        mmaQ(aC, b0, 0, 0);
        if (mode != 2) BAR();
        // p2: issue B1c reads | MFMA Q10(aN=A1, b0)
        readB(buf, 1, b1);
        mmaQ(aN, b0, 1, 0);
        if (mode != 2) BAR();   // all waves' A reads (mh0 prev-p4, mh1 p1) drained
        // p3: stage whole A(kt+2); counted wait for kt+1 | MFMA Q11(aN, b1)
        if (mode == 0) { stageA(kt + 2, 0); stageA(kt + 2, 1); VM4(); }
        else if (mode == 1) { VM0(); }
        mmaQ(aN, b1, 1, 1);
        if (mode != 2) BAR();   // all waves' B reads (nh0 prev-p4, nh1 p2) drained
        // p4: stage whole B(kt+2); cross-tile A0/B0 reads (other buffer)
        //     into dead slots | MFMA Q01(aC, b1)
        if (mode == 0) { stageB(kt + 2, 0); stageB(kt + 2, 1); }
        if (mode != 2) {
            SB0();
            readA(buf ^ 1, 0, aN);
            readB(buf ^ 1, 0, b0);
        }
        mmaQ(aC, b1, 0, 1);
        if (mode != 2) BAR();
    };

    // ---- prologue: stage tiles 0 and 1; tile0 landed; prime A0/B0 reads
    stageA(0, 0); stageA(0, 1); stageB(0, 0); stageB(0, 1);
    stageA(1, 0); stageA(1, 1); stageB(1, 0); stageB(1, 1);
    VM8();
    BAR(); SB0();
    readA(0, 0, aX);
    readB(0, 0, b0);

    // main loop unrolled by 2 for the A-slot ping-pong (NT-2 = 62, even)
    for (int kt = 0; kt < NT - 2; kt += 2) {
        tileT(kt,     aX, aY, 0);
        tileT(kt + 1, aY, aX, 0);
    }
    tileT(NT - 2, aX, aY, 1);   // drain: VM0, read tile NT-1's A0/B0
    tileT(NT - 1, aY, aX, 2);   // compute only

    // ---- epilogue: 32x32 C/D: col = lane&31, row = (reg&3)+8*(reg>>2)+4*(lane>>5)
    float bb[2];
#pragma unroll
    for (int an = 0; an < 2; an++)
        bb[an] = bias[n0 + wn + an * 32 + l31];

#pragma unroll
    for (int am = 0; am < 4; am++) {
        const int gmb = m0 + wm + am * 32 + 4 * khalf;
#pragma unroll
        for (int an = 0; an < 2; an++) {
            const int gn = n0 + wn + an * 32 + l31;
#pragma unroll
            for (int reg = 0; reg < 16; reg++) {
                const int gr = gmb + (reg & 3) + 8 * (reg >> 2);
                out[(size_t)gr * N_TOT + gn] = acc[am][an][reg] + bb[an];
            }
        }
    }
}

extern "C" void kernel_launch(void* const* d_in, const int* in_sizes, int n_in,
                              void* d_out, int out_size, void* d_ws, size_t ws_size,
                              hipStream_t stream) {
    const float* data   = (const float*)d_in[0];   // [4,2048,4096]
    const float* weight = (const float*)d_in[1];   // [4096,4096]
    const float* w_mask = (const float*)d_in[2];   // [4096,4096]
    const float* bias_p = (const float*)d_in[3];   // [4096]
    float* out = (float*)d_out;

    // Workspace layout: A_bf16 [M*K] then W_bf16 [N*K]  (96 MB total)
    unsigned short* a_bf = (unsigned short*)d_ws;
    unsigned short* w_bf = a_bf + (size_t)M_TOT * K_TOT;

    cast_data_kernel<<<(M_TOT * K_TOT) / (256 * 4), 256, 0, stream>>>(
        (const float4*)data, (ushort4*)a_bf);
    cast_w_kernel<<<(N_TOT * K_TOT) / (256 * 4), 256, 0, stream>>>(
        (const float4*)weight, (const float4*)w_mask, (ushort4*)w_bf);

    dim3 grid(N_TOT / BN, M_TOT / BM);   // (16, 32)
    gemm_bt_kernel<<<grid, 512, 0, stream>>>(a_bf, w_bf, bias_p, out);
}